// Round 13
// baseline (272.488 us; speedup 1.0000x reference)
//
#include <hip/hip_runtime.h>

// GraphSAGE 2-layer: CSR gather-mean (bf16) + bf16 MFMA fused GEMMs.
// R13: (a) scan_bsum merged into scatter_offs (9 launches); (b) gather uses
//      4 independent accumulator chains (3-4 row loads in flight/wave).
//      GEMM identical to R12 (memory-floor'd at ~60us; 4 schedules converged).

constexpr int NN   = 100000;
constexpr int NE   = 625000;
constexpr int DIN  = 128;
constexpr int DHID = 256;
constexpr int NB   = (NN + 255) / 256;          // 391 scan chunks
constexpr int CONV_BLKS = NN * DIN / 8 / 256;   // 6250 (exact)

using short8 = __attribute__((ext_vector_type(8))) short;
using f32x4  = __attribute__((ext_vector_type(4))) float;

__device__ __forceinline__ float bf2f(unsigned int u) {
    return __uint_as_float(u << 16);
}
__device__ __forceinline__ unsigned short f2b(float f) {
    unsigned int u = __float_as_uint(f);
    unsigned int r = (u + 0x7fffu + ((u >> 16) & 1u)) >> 16;   // RNE
    return (unsigned short)r;
}
__device__ __forceinline__ unsigned int pack2(float lo, float hi) {
    return (unsigned int)f2b(lo) | ((unsigned int)f2b(hi) << 16);
}
__device__ __forceinline__ void gload16(const void* g, void* lds) {
    __builtin_amdgcn_global_load_lds(
        (const __attribute__((address_space(1))) void*)g,
        (__attribute__((address_space(3))) void*)lds, 16, 0, 0);
}

// ---------------- CSR build ------------------------------------------------
__global__ __launch_bounds__(256) void hist_kernel(const int* __restrict__ dst,
                                                   int* __restrict__ hist)
{
    int t = blockIdx.x * 256 + threadIdx.x;
    if (t < NE) atomicAdd(&hist[dst[t]], 1);
}

__global__ __launch_bounds__(256) void chunk_sum_kernel(const int* __restrict__ hist,
                                                        int* __restrict__ bsum)
{
    __shared__ int s[256];
    int i = blockIdx.x * 256 + threadIdx.x;
    s[threadIdx.x] = (i < NN) ? hist[i] : 0;
    __syncthreads();
    for (int off = 128; off > 0; off >>= 1) {
        if (threadIdx.x < off) s[threadIdx.x] += s[threadIdx.x + off];
        __syncthreads();
    }
    if (threadIdx.x == 0) bsum[blockIdx.x] = s[0];
}

// per-chunk exclusive scan; each block also redundantly computes its own
// bsum-prefix (<=391 ints, 2/thread) -- replaces the separate scan kernel.
__global__ __launch_bounds__(256) void scatter_offs_kernel(
    const int* __restrict__ hist, const int* __restrict__ bsum,
    int* __restrict__ offs, int* __restrict__ cursor)
{
    __shared__ int s[256];
    const int t = threadIdx.x;
    const int b = blockIdx.x;

    // 1) prefix = sum of bsum[0..b)
    int acc = 0;
    for (int i = t; i < b; i += 256) acc += bsum[i];
    s[t] = acc;
    __syncthreads();
    for (int off = 128; off > 0; off >>= 1) {
        if (t < off) s[t] += s[t + off];
        __syncthreads();
    }
    const int bpre = s[0];
    __syncthreads();

    // 2) local exclusive scan of this chunk
    int i = b * 256 + t;
    int v = (i < NN) ? hist[i] : 0;
    s[t] = v;
    __syncthreads();
    for (int off = 1; off < 256; off <<= 1) {
        int u = (t >= off) ? s[t - off] : 0;
        __syncthreads();
        s[t] += u;
        __syncthreads();
    }
    int excl = s[t] - v + bpre;
    if (i < NN) {
        offs[i]   = excl;
        cursor[i] = excl;
    }
    if (i == NN - 1) offs[NN] = NE;
}

__global__ __launch_bounds__(256) void perm_kernel(const int* __restrict__ src,
                                                   const int* __restrict__ dst,
                                                   int* __restrict__ cursor,
                                                   int* __restrict__ perm)
{
    int t = blockIdx.x * 256 + threadIdx.x;
    if (t < NE) {
        int p = atomicAdd(&cursor[dst[t]], 1);
        perm[p] = src[t];
    }
}

// ---------------- merged prep: x->bf16, WT0, WT1, zero hist ----------------
__global__ __launch_bounds__(256) void prep_all_kernel(
    const float* __restrict__ x, unsigned short* __restrict__ xb,
    const float* __restrict__ Wl0, const float* __restrict__ Wr0,
    unsigned short* __restrict__ WT0,
    const float* __restrict__ Wl1, const float* __restrict__ Wr1,
    unsigned short* __restrict__ WT1,
    int* __restrict__ hist)
{
    int b = blockIdx.x;
    if (b < CONV_BLKS) {
        int t = b * 256 + threadIdx.x;          // [0, 1.6M) exact
        float4 v0 = reinterpret_cast<const float4*>(x)[t * 2 + 0];
        float4 v1 = reinterpret_cast<const float4*>(x)[t * 2 + 1];
        uint4 o;
        o.x = pack2(v0.x, v0.y); o.y = pack2(v0.z, v0.w);
        o.z = pack2(v1.x, v1.y); o.w = pack2(v1.z, v1.w);
        reinterpret_cast<uint4*>(xb)[t] = o;
    } else if (b < CONV_BLKS + 256) {
        int t = (b - CONV_BLKS) * 256 + threadIdx.x;   // [0, 65536)
        int n = t >> 8, k = t & 255;
        float v = (k < DIN) ? Wl0[(size_t)k * DHID + n]
                            : Wr0[(size_t)(k - DIN) * DHID + n];
        WT0[t] = f2b(v);
    } else if (b < CONV_BLKS + 256 + 512) {
        int t = (b - CONV_BLKS - 256) * 256 + threadIdx.x;   // [0, 131072)
        int n = t >> 9, k = t & 511;
        float v = (k < DHID) ? Wl1[(size_t)k * DHID + n]
                             : Wr1[(size_t)(k - DHID) * DHID + n];
        WT1[t] = f2b(v);
    } else {
        int t = (b - CONV_BLKS - 256 - 512) * 256 + threadIdx.x;
        if (t < NN) hist[t] = 0;
    }
}

// ---------------- gather-mean aggregation (4 independent chains) -----------
// One wave per node. Lane l: half h = l>>5 (even/odd edge of a pair),
// col-chunk c = l&31. Pairs distributed round-robin over 4 accumulator
// chains -> 3-4 independent row loads in flight for typical degrees.
template <int D>
__global__ __launch_bounds__(256) void gather_mean_kernel(
    const int* __restrict__ offs, const int* __restrict__ perm,
    const unsigned short* __restrict__ feat, unsigned short* __restrict__ agg)
{
    const int w = (blockIdx.x * 256 + threadIdx.x) >> 6;
    const int l = threadIdx.x & 63;
    const int h = l >> 5;
    const int c = l & 31;
    if (w >= NN) return;
    const int beg = offs[w], end = offs[w + 1];
    const int deg = end - beg;
    const float sc = 1.0f / (float)(deg > 1 ? deg : 1);

    if constexpr (D == 256) {
        const uint4* base = reinterpret_cast<const uint4*>(feat);  // 32/row
        float A0[8] = {}, A1[8] = {}, A2[8] = {}, A3[8] = {};
        for (int e0 = 0; e0 < deg; e0 += 64) {
            const int chunk = min(deg - e0, 64);
            int pv = (l < chunk) ? perm[beg + e0 + l] : 0;
            auto dopair = [&](float* A, int p) {
                int sA = __builtin_amdgcn_readlane(pv, 2 * p);
                int sB = __builtin_amdgcn_readlane(pv, 2 * p + 1);
                int e  = 2 * p + h;
                int s  = h ? sB : sA;
                float m = (e < chunk) ? 1.0f : 0.0f;
                uint4 v = base[(size_t)s * 32 + c];
                A[0] = fmaf(bf2f(v.x & 0xffffu), m, A[0]);
                A[1] = fmaf(bf2f(v.x >> 16),     m, A[1]);
                A[2] = fmaf(bf2f(v.y & 0xffffu), m, A[2]);
                A[3] = fmaf(bf2f(v.y >> 16),     m, A[3]);
                A[4] = fmaf(bf2f(v.z & 0xffffu), m, A[4]);
                A[5] = fmaf(bf2f(v.z >> 16),     m, A[5]);
                A[6] = fmaf(bf2f(v.w & 0xffffu), m, A[6]);
                A[7] = fmaf(bf2f(v.w >> 16),     m, A[7]);
            };
            const int np = (chunk + 1) >> 1;
            int p = 0;
            for (; p + 4 <= np; p += 4) {
                dopair(A0, p); dopair(A1, p + 1);
                dopair(A2, p + 2); dopair(A3, p + 3);
            }
            if (p     < np) dopair(A0, p);
            if (p + 1 < np) dopair(A1, p + 1);
            if (p + 2 < np) dopair(A2, p + 2);
        }
        float r[8];
        #pragma unroll
        for (int j = 0; j < 8; ++j) {
            r[j] = (A0[j] + A1[j]) + (A2[j] + A3[j]);
            r[j] += __shfl_xor(r[j], 32);
            r[j] *= sc;
        }
        if (l < 32) {
            uint4 o;
            o.x = pack2(r[0], r[1]); o.y = pack2(r[2], r[3]);
            o.z = pack2(r[4], r[5]); o.w = pack2(r[6], r[7]);
            reinterpret_cast<uint4*>(agg)[(size_t)w * 32 + c] = o;
        }
    } else {   // D == 128: 32 x uint2 per row
        const uint2* base = reinterpret_cast<const uint2*>(feat);
        float A0[4] = {}, A1[4] = {}, A2[4] = {}, A3[4] = {};
        for (int e0 = 0; e0 < deg; e0 += 64) {
            const int chunk = min(deg - e0, 64);
            int pv = (l < chunk) ? perm[beg + e0 + l] : 0;
            auto dopair = [&](float* A, int p) {
                int sA = __builtin_amdgcn_readlane(pv, 2 * p);
                int sB = __builtin_amdgcn_readlane(pv, 2 * p + 1);
                int e  = 2 * p + h;
                int s  = h ? sB : sA;
                float m = (e < chunk) ? 1.0f : 0.0f;
                uint2 v = base[(size_t)s * 32 + c];
                A[0] = fmaf(bf2f(v.x & 0xffffu), m, A[0]);
                A[1] = fmaf(bf2f(v.x >> 16),     m, A[1]);
                A[2] = fmaf(bf2f(v.y & 0xffffu), m, A[2]);
                A[3] = fmaf(bf2f(v.y >> 16),     m, A[3]);
            };
            const int np = (chunk + 1) >> 1;
            int p = 0;
            for (; p + 4 <= np; p += 4) {
                dopair(A0, p); dopair(A1, p + 1);
                dopair(A2, p + 2); dopair(A3, p + 3);
            }
            if (p     < np) dopair(A0, p);
            if (p + 1 < np) dopair(A1, p + 1);
            if (p + 2 < np) dopair(A2, p + 2);
        }
        float r[4];
        #pragma unroll
        for (int j = 0; j < 4; ++j) {
            r[j] = (A0[j] + A1[j]) + (A2[j] + A3[j]);
            r[j] += __shfl_xor(r[j], 32);
            r[j] *= sc;
        }
        if (l < 32) {
            uint2 o;
            o.x = pack2(r[0], r[1]); o.y = pack2(r[2], r[3]);
            reinterpret_cast<uint2*>(agg)[(size_t)w * 32 + c] = o;
        }
    }
}

// ---------------- bf16 MFMA fused SAGE GEMM (256x256, 16 waves, 2-buf) -----
// out[m,c] = relu( [agg | xr][m,:] @ WT^T + bias ),  WT is [256][2KP] bf16.
// 1024 threads = 16 waves (4 wr x 4 wc), wave tile 64x64, BK=32.
// LDS: 2 buffers x (A 16KB + B 16KB) = 64 KB -> 2 blocks/CU = 32 waves/CU.
// Swizzle (verified, conflicts=0): LDS chunk c holds global chunk
// c ^ ((row>>1)&3); staging source chunk = (l&3) ^ ((l>>3)&3).
// Pipeline: 1-deep prefetch, steady vmcnt(2), raw barriers.
template <int KP, bool WF, bool WB>
__global__ __launch_bounds__(1024) void sage_mfma_gemm(
    const unsigned short* __restrict__ Aagg,  // [M, KP] bf16
    const unsigned short* __restrict__ Axr,   // [M, KP] bf16
    const unsigned short* __restrict__ WT,    // [256, 2KP] bf16
    const float* __restrict__ bias,
    float* __restrict__ outf,                 // used if WF
    unsigned short* __restrict__ outb,        // used if WB
    int M)
{
    __shared__ __align__(16) unsigned short As[2 * 8192];   // 2 x [256][32]
    __shared__ __align__(16) unsigned short Bs[2 * 8192];   // 2 x [256][32]

    const int t   = threadIdx.x;
    const int l   = t & 63;
    const int wid = t >> 6;          // 0..15
    const int wr  = wid >> 2;        // 0..3
    const int wc  = wid & 3;         // 0..3
    const int m0  = blockIdx.x * 256;

    const int rin = l >> 2;                       // row within 16-row chunk
    const int csw = (l & 3) ^ ((l >> 3) & 3);     // swizzled source chunk

    // 32 chunks per K-tile (16 A + 16 B); this wave stages 2*wid, 2*wid+1
    const int sc0 = wid * 2, sc1 = sc0 + 1;

    constexpr int K2 = 2 * KP;
    constexpr int KT = K2 / 32;

    auto stageChunk = [&](int buf, int kt, int ch) {
        const int kb = kt * 32;
        if (ch < 16) {              // A chunk: rows m0+ch*16 .. +16
            const unsigned short* Asrc;
            int kk;
            if (kb < KP) { Asrc = Aagg; kk = kb; }
            else         { Asrc = Axr;  kk = kb - KP; }
            int row = m0 + ch * 16 + rin; if (row >= M) row = M - 1;
            gload16(Asrc + (size_t)row * KP + kk + csw * 8,
                    As + buf * 8192 + ch * 512);
        } else {                    // B chunk: WT rows (ch-16)*16 .. +16
            int row = (ch - 16) * 16 + rin;
            gload16(WT + (size_t)row * K2 + kb + csw * 8,
                    Bs + buf * 8192 + (ch - 16) * 512);
        }
    };
    auto stage = [&](int buf, int kt) {
        stageChunk(buf, kt, sc0);
        stageChunk(buf, kt, sc1);
    };

    // fragment-read offsets: row fr = l&15, logical chunk g = l>>4,
    // lds chunk = g ^ ((fr>>1)&3) = (l>>4) ^ ((l>>1)&3)
    const int fr  = l & 15;
    const int swz = ((l >> 4) ^ ((l >> 1) & 3)) * 8;    // ushort units
    const int aOff = (wr * 64 + fr) * 32 + swz;
    const int bOff = (wc * 64 + fr) * 32 + swz;

    f32x4 acc[4][4] = {};

    stage(0, 0);

    int cur = 0;
    for (int kt = 0; kt < KT; ++kt) {
        if (kt + 1 < KT) {
            stage(cur ^ 1, kt + 1);   // 1-deep prefetch (2 more loads)
            asm volatile("s_waitcnt vmcnt(2)" ::: "memory");   // tile kt landed
        } else {
            asm volatile("s_waitcnt vmcnt(0)" ::: "memory");
        }
        __builtin_amdgcn_s_barrier();            // raw: no auto drain
        __builtin_amdgcn_sched_barrier(0);

        const unsigned short* Ard = As + cur * 8192 + aOff;
        const unsigned short* Brd = Bs + cur * 8192 + bOff;
        short8 af[4], bf[4];
        #pragma unroll
        for (int i = 0; i < 4; ++i)
            af[i] = *reinterpret_cast<const short8*>(Ard + i * 512);
        #pragma unroll
        for (int i = 0; i < 4; ++i)
            bf[i] = *reinterpret_cast<const short8*>(Brd + i * 512);
        #pragma unroll
        for (int i = 0; i < 4; ++i)
            #pragma unroll
            for (int j = 0; j < 4; ++j)
                acc[i][j] = __builtin_amdgcn_mfma_f32_16x16x32_bf16(
                    af[i], bf[j], acc[i][j], 0, 0, 0);

        asm volatile("s_waitcnt lgkmcnt(0)" ::: "memory");  // reads done
        __builtin_amdgcn_s_barrier();            // safe to overwrite cur
        __builtin_amdgcn_sched_barrier(0);
        cur ^= 1;
    }

    // epilogue: C/D layout col = l&15, row = (l>>4)*4 + reg
    const int rq = (l >> 4) * 4;
    #pragma unroll
    for (int fn = 0; fn < 4; ++fn) {
        const int col = wc * 64 + fn * 16 + fr;
        const float bb = bias[col];
        #pragma unroll
        for (int fm = 0; fm < 4; ++fm) {
            const int rbase = m0 + wr * 64 + fm * 16 + rq;
            #pragma unroll
            for (int j = 0; j < 4; ++j) {
                const int r = rbase + j;
                if (r < M) {
                    float v = fmaxf(acc[fm][fn][j] + bb, 0.f);
                    if (WF) outf[(size_t)r * DHID + col] = v;
                    if (WB) outb[(size_t)r * DHID + col] = f2b(v);
                }
            }
        }
    }
}

extern "C" void kernel_launch(void* const* d_in, const int* in_sizes, int n_in,
                              void* d_out, int out_size, void* d_ws, size_t ws_size,
                              hipStream_t stream)
{
    const float* x   = (const float*)d_in[0];
    const int*   ei  = (const int*)d_in[1];
    const int*   src = ei;
    const int*   dst = ei + NE;
    const float* Wl0 = (const float*)d_in[2];
    const float* Wr0 = (const float*)d_in[3];
    const float* b0  = (const float*)d_in[4];
    const float* Wl1 = (const float*)d_in[5];
    const float* Wr1 = (const float*)d_in[6];
    const float* b1  = (const float*)d_in[7];
    float* out = (float*)d_out;

    // workspace layout (bytes):
    //   hist    : @0          400384
    //   offs    : @400384     400640
    //   perm    : @801024     2500352
    //   bsum    : @3301376    4096
    //   (spare) : @3305472    4096
    //   cursor  : @3309568    400384
    //   WT0     : @3709952    131072
    //   WT1     : @3841024    262144
    //   xb      : @4103168    25600000
    //   h0b     : @29703168   51200000
    //   aggb    : @80903168   51200000
    // total ~132.1 MB
    char* ws = (char*)d_ws;
    int*            hist   = (int*)(ws);
    int*            offs   = (int*)(ws + 400384);
    int*            perm   = (int*)(ws + 801024);
    int*            bsum   = (int*)(ws + 3301376);
    int*            cursor = (int*)(ws + 3309568);
    unsigned short* WT0    = (unsigned short*)(ws + 3709952);
    unsigned short* WT1    = (unsigned short*)(ws + 3841024);
    unsigned short* xb     = (unsigned short*)(ws + 4103168);
    unsigned short* h0b    = (unsigned short*)(ws + 29703168);
    unsigned short* aggb   = (unsigned short*)(ws + 80903168);

    // prep (also zeroes hist), then CSR chain (scan fused into scatter_offs)
    prep_all_kernel<<<CONV_BLKS + 256 + 512 + NB, 256, 0, stream>>>(
        x, xb, Wl0, Wr0, WT0, Wl1, Wr1, WT1, hist);
    hist_kernel<<<(NE + 255) / 256, 256, 0, stream>>>(dst, hist);
    chunk_sum_kernel<<<NB, 256, 0, stream>>>(hist, bsum);
    scatter_offs_kernel<<<NB, 256, 0, stream>>>(hist, bsum, offs, cursor);
    perm_kernel<<<(NE + 255) / 256, 256, 0, stream>>>(src, dst, cursor, perm);

    constexpr int NWBLK = (NN * 64) / 256;     // 25000 exactly
    const int GEMM_BLKS = (NN + 255) / 256;    // 391 blocks, full N per block

    // ---- layer 0 ----
    gather_mean_kernel<DIN><<<NWBLK, 256, 0, stream>>>(offs, perm, xb, aggb);
    sage_mfma_gemm<DIN, false, true><<<GEMM_BLKS, 1024, 0, stream>>>(
        aggb, xb, WT0, b0, nullptr, h0b, NN);

    // ---- layer 1 ----
    gather_mean_kernel<DHID><<<NWBLK, 256, 0, stream>>>(offs, perm, h0b, aggb);
    sage_mfma_gemm<DHID, true, false><<<GEMM_BLKS, 1024, 0, stream>>>(
        aggb, h0b, WT1, b1, out, nullptr, NN);
}